// Round 15
// baseline (1874.042 us; speedup 1.0000x reference)
//
#include <hip/hip_runtime.h>
#include <cstdint>
#include <cstddef>

typedef __bf16 bf16x8 __attribute__((ext_vector_type(8)));
typedef float f32x4 __attribute__((ext_vector_type(4)));

#define HD 256
#define TLEN 1000
#define NSTEP 999
#define BTILE 4

// ws layout (bf16 elements): W1F | W1C | W2R | W3R | W4R, fragment-ordered.
#define W1F_OFF 0
#define W1C_OFF 8192
#define W2R_OFF 16384
#define W3R_OFF 81920
#define W4R_OFF 147456
#define WS_ELEMS 151552

__device__ __forceinline__ void wg_barrier() {
  // LDS-only drain + barrier: do NOT force vmcnt(0) like __syncthreads does,
  // so the z-prefetch / out-stores stay in flight across layer barriers.
  asm volatile("s_waitcnt lgkmcnt(0)\n\ts_barrier" ::: "memory");
}

// Repack fp32 weights -> bf16 MFMA A-fragments in ws (r13 layout, unchanged).
// Layer-1 algebraic fold (verified r13, absmax 0.25):
//   h1_pre = x*W1x + z_eff*W1z + c1
//   W1F: k0-7 = W1[16+k]+W1[32+k]; k8-15 = W1[24+(k-8)]+W1[40+(k-8)]; else 0
//   W1C: k0-7 = W1[k]-W1[16+k]; k8-15 = W1[8+(k-8)]-W1[24+(k-8)]; k16 = b1
// W2/W3/W4: k = kb*32 + (lane>>4)*8 + j ; n = w*32 + tt*16 + (lane&15)
__global__ void prep_weights(const float* __restrict__ W1, const float* __restrict__ b1,
                             const float* __restrict__ W2, const float* __restrict__ W3,
                             const float* __restrict__ W4, __bf16* __restrict__ ws) {
  int tid = blockIdx.x * blockDim.x + threadIdx.x;
  if (tid >= WS_ELEMS) return;
  float val = 0.0f;
  if (tid < W1C_OFF) {                       // W1F: 8w x 2tt x 64lane x 8j
    int t = tid;
    int j = t & 7, lane = (t >> 3) & 63, tt = (t >> 9) & 1, w = (t >> 10) & 7;
    int k = ((lane >> 4) * 8) + j;
    int n = w * 32 + tt * 16 + (lane & 15);
    if (k < 8) val = W1[(16 + k) * HD + n] + W1[(32 + k) * HD + n];
    else if (k < 16) { int d = k - 8; val = W1[(24 + d) * HD + n] + W1[(40 + d) * HD + n]; }
  } else if (tid < W2R_OFF) {                // W1C
    int t = tid - W1C_OFF;
    int j = t & 7, lane = (t >> 3) & 63, tt = (t >> 9) & 1, w = (t >> 10) & 7;
    int k = ((lane >> 4) * 8) + j;
    int n = w * 32 + tt * 16 + (lane & 15);
    if (k < 8) val = W1[k * HD + n] - W1[(16 + k) * HD + n];
    else if (k < 16) { int d = k - 8; val = W1[(8 + d) * HD + n] - W1[(24 + d) * HD + n]; }
    else if (k == 16) val = b1[n];
  } else if (tid < W3R_OFF) {                // W2R: 8w x 8kb x 2tt x 64 x 8
    int t = tid - W2R_OFF;
    int j = t & 7, lane = (t >> 3) & 63, tt = (t >> 9) & 1, kb = (t >> 10) & 7, w = (t >> 13) & 7;
    int k = kb * 32 + ((lane >> 4) * 8) + j;
    int n = w * 32 + tt * 16 + (lane & 15);
    val = W2[k * HD + n];
  } else if (tid < W4R_OFF) {                // W3R
    int t = tid - W3R_OFF;
    int j = t & 7, lane = (t >> 3) & 63, tt = (t >> 9) & 1, kb = (t >> 10) & 7, w = (t >> 13) & 7;
    int k = kb * 32 + ((lane >> 4) * 8) + j;
    int n = w * 32 + tt * 16 + (lane & 15);
    val = W3[k * HD + n];
  } else {                                   // W4R: 8kb x 64 x 8, N padded 8->16 with zeros
    int t = tid - W4R_OFF;
    int j = t & 7, lane = (t >> 3) & 63, kb = (t >> 9) & 7;
    int k = kb * 32 + ((lane >> 4) * 8) + j;
    int n = lane & 15;
    val = (n < 8) ? W4[k * 8 + n] : 0.0f;
  }
  ws[tid] = (__bf16)val;
}

// (resubmit after infra failure — kernel unchanged from r14)
// r13 champion (fold, 1585us, VGPR 116) + the tail finish:
//  (1) bfr/h4r de-persisted via SAFE-ROW BROADCAST reads (rrow = live?bcol:0):
//      dead lanes read row 0's live data at the same addresses as bcol-0 lanes
//      (LDS broadcast, free; bank pattern unchanged) -> -36 persistent regs.
//      Dead C-cols get finite garbage that is never read anywhere.
//  (2) D-merge: all waves redundantly reduce p4 -> Euler per-lane in x4 regs
//      (q<2); shfl_xor(16) builds the folded-L1 x-frag; z_eff publishes in
//      phase B (WAR: 1 bar after reads; RAW: 2 bars before next reads).
//      3 barriers/step, no wave-0 serial section, no x LDS round trip.
__global__ __launch_bounds__(512, 2) void ode_main(
    const float* __restrict__ t_g, const float* __restrict__ x_g,
    const float* __restrict__ z_g, const float* __restrict__ ev_g,
    const float* __restrict__ zj_g, const float* __restrict__ b2_g,
    const float* __restrict__ b3_g, const float* __restrict__ b4_g,
    const __bf16* __restrict__ ws, float* __restrict__ out) {
  __shared__ __align__(16) __bf16 h_a[16 * 264];   // 16 rows kept (4 live), row 528B
  __shared__ __align__(16) __bf16 h_b[16 * 264];
  __shared__ __align__(16) float p4[8 * 128];      // [wave][bcol*8 + q*4 .. +3]
  __shared__ __align__(16) float z_eff[16 * 12];
  __shared__ __align__(16) float x0s[16 * 12];
  __shared__ __align__(16) float z0s[16 * 12];
  __shared__ __align__(16) float zjs[16 * 12];
  __shared__ float evs[16];

  const int tid  = threadIdx.x;
  const int lane = tid & 63;
  const int wid  = tid >> 6;     // 8 waves; wave w owns hidden cols [32w, 32w+32)
  const int bcol = lane & 15;    // B/C-operand column; batch row if < BTILE
  const int q    = lane >> 4;    // quad
  const int b0   = blockIdx.x * BTILE;
  const bool live = bcol < BTILE;
  const int rrow = live ? bcol : 0;                    // broadcast-safe read row
  const size_t gb = (size_t)(b0 + (live ? bcol : 0));  // masked use only

  // ---- stage per-batch constants (rows >= BTILE zeroed) + zero p4 ----
  if (tid < 128) {
    int m = tid >> 3, d = tid & 7;
    if (m < BTILE) {
      size_t g = (size_t)(b0 + m);
      x0s[m * 12 + d] = x_g[g * (TLEN * 8) + d];
      z0s[m * 12 + d] = z_g[g * (TLEN * 8) + d];
      zjs[m * 12 + d] = zj_g[g * 8 + d];
      if (d == 0) evs[m] = ev_g[g];
    } else {
      x0s[m * 12 + d] = 0.f;
      z0s[m * 12 + d] = 0.f;
      zjs[m * 12 + d] = 0.f;
      if (d == 0) evs[m] = 0.f;
    }
  }
  if (tid < 512) { p4[tid] = 0.f; p4[tid + 512] = 0.f; }
  __syncthreads();

  if (tid < 128) {  // z_eff for step 0 (rows >= BTILE resolve to 0)
    int m = tid >> 3, d = tid & 7;
    float t0 = t_g[0];
    z_eff[m * 12 + d] = (t0 >= evs[m]) ? zjs[m * 12 + d] : z0s[m * 12 + d];
  }

  // ---- resident weight fragments (A-operand layout) ----
  const bf16x8* wsv = (const bf16x8*)ws;
  bf16x8 w1ff[2], w2f[8][2], w3f[8][2];
#pragma unroll
  for (int tt = 0; tt < 2; ++tt)
    w1ff[tt] = wsv[(W1F_OFF / 8) + (wid * 2 + tt) * 64 + lane];
#pragma unroll
  for (int kb = 0; kb < 8; ++kb)
#pragma unroll
    for (int tt = 0; tt < 2; ++tt) {
      w2f[kb][tt] = wsv[(W2R_OFF / 8) + ((wid * 8 + kb) * 2 + tt) * 64 + lane];
      w3f[kb][tt] = wsv[(W3R_OFF / 8) + ((wid * 8 + kb) * 2 + tt) * 64 + lane];
    }
  bf16x8 w4f = wsv[(W4R_OFF / 8) + wid * 64 + lane];  // W4 k-slice for this wave

  // biases as C-init: lane's 4 C rows are hidden n = wid*32 + tt*16 + q*4 + e
  f32x4 b2v[2], b3v[2];
#pragma unroll
  for (int tt = 0; tt < 2; ++tt) {
    int n0 = wid * 32 + tt * 16 + q * 4;
    b2v[tt] = *(const f32x4*)(b2_g + n0);
    b3v[tt] = *(const f32x4*)(b3_g + n0);
  }
  f32x4 b4v = {0.f, 0.f, 0.f, 0.f};
  if (q < 2) b4v = *(const f32x4*)(b4_g + q * 4);   // live out dims on q<2 lanes

  // wave-2 personals (z_eff producer): lanes 0..15 cover (m 0..3) x (d pairs)
  const int m1 = lane >> 2;
  const int d0 = (lane & 3) * 2;
  float2 zjf = make_float2(0.f, 0.f);
  float ev1 = 0.f;
  const bool zprod = (wid == 2) && (lane < BTILE * 4);
  if (zprod) {
    zjf.x = zjs[m1 * 12 + d0];
    zjf.y = zjs[m1 * 12 + d0 + 1];
    ev1 = evs[m1];
  }

  bf16x8 zf;
#pragma unroll
  for (int e = 0; e < 8; ++e) zf[e] = (__bf16)0.f;

  // ---- c1init: step-invariant layer-1 term via ONE-SHOT MFMA on W1C ----
  f32x4 c1init[2];
  {
    bf16x8 cfrag = zf;
    if (q == 0) {
      const float* xp = x0s + bcol * 12;
#pragma unroll
      for (int e = 0; e < 4; ++e) { cfrag[e] = (__bf16)xp[e]; cfrag[e + 4] = (__bf16)xp[e + 4]; }
    } else if (q == 1) {
      const float* zp = z0s + bcol * 12;
#pragma unroll
      for (int e = 0; e < 4; ++e) { cfrag[e] = (__bf16)zp[e]; cfrag[e + 4] = (__bf16)zp[e + 4]; }
    } else if (q == 2) {
      cfrag[0] = (__bf16)1.0f;                 // b1 row at k=16
    }
    f32x4 z4 = {0.f, 0.f, 0.f, 0.f};
#pragma unroll
    for (int tt = 0; tt < 2; ++tt) {
      bf16x8 w1cf = wsv[(W1C_OFF / 8) + (wid * 2 + tt) * 64 + lane];
      c1init[tt] = __builtin_amdgcn_mfma_f32_16x16x32_bf16(w1cf, cfrag, z4, 0, 0, 0);
    }
  }

  // per-lane x state: q0 holds dims 0-3, q1 holds dims 4-7 of batch bcol
  f32x4 x4 = {0.f, 0.f, 0.f, 0.f};
  if (q < 2) x4 = *(const f32x4*)(x0s + bcol * 12 + q * 4);

  __syncthreads();

  float tc = t_g[0];
  float tn_hold = tc;

  auto layer = [&](const __bf16* src, __bf16* dst, const bf16x8 (*wf)[2], const f32x4* bv) {
    const bf16x8* hp = (const bf16x8*)src;
    bf16x8 bfr[8];   // TRANSIENT: broadcast-safe reads, no exec masking
#pragma unroll
    for (int kb = 0; kb < 8; ++kb) bfr[kb] = hp[rrow * 33 + kb * 4 + q];  // ds_read_b128 x8
#pragma unroll
    for (int tt = 0; tt < 2; ++tt) {
      f32x4 c = bv[tt];
#pragma unroll
      for (int kb = 0; kb < 8; ++kb)
        c = __builtin_amdgcn_mfma_f32_16x16x32_bf16(wf[kb][tt], bfr[kb], c, 0, 0, 0);
      union { __bf16 h4[4]; unsigned long long u; } pk;
#pragma unroll
      for (int e = 0; e < 4; ++e) {
        float v = c[e];
        v = (v > 0.f) ? v : (__expf(v) - 1.0f);  // ELU
        pk.h4[e] = (__bf16)v;
      }
      if (live)
        *(unsigned long long*)(dst + bcol * 264 + wid * 32 + tt * 16 + q * 4) = pk.u;
    }
  };

#pragma unroll 1
  for (int i = 0; i <= NSTEP; ++i) {
    // ---- phase A: finish step i-1 (all-wave p4 reduce -> x4 regs) + L1 of step i ----
    float tn = tn_hold;
    float dt = tn - tc;   // dt = 0 at i = 0 (p4 zero-inited -> x4 = x0)
    tc = tn;
    if (q < 2 && live) {
      const float* pp = p4 + bcol * 8 + q * 4;
      f32x4 s = {0.f, 0.f, 0.f, 0.f};
#pragma unroll
      for (int j = 0; j < 8; ++j) s += *(const f32x4*)(pp + j * 128);
#pragma unroll
      for (int e = 0; e < 4; ++e) x4[e] += dt * (s[e] + b4v[e]);
      if (wid == 0)   // fire-and-forget; wg_barrier never drains vmcnt
        *(f32x4*)(out + gb * (TLEN * 8) + (size_t)i * 8 + q * 4) = x4;
    }
    if (i == NSTEP) break;   // uniform exit after storing out[:, NSTEP]

    float2 zpre = make_float2(0.f, 0.f);
    if (zprod)  // prefetch z[:, i+1] (in-bounds: i+1 <= NSTEP); used in phase B
      zpre = *(const float2*)(z_g + ((size_t)(b0 + m1) * TLEN + (i + 1)) * 8 + d0);

    // folded layer-1 B-frag: q0 = x (all 8 dims via shfl_xor 16), q1 = z_eff, else 0
    f32x4 xo;
#pragma unroll
    for (int e = 0; e < 4; ++e) xo[e] = __shfl_xor(x4[e], 16);
    bf16x8 f = zf;
    if (q == 0) {
#pragma unroll
      for (int e = 0; e < 4; ++e) { f[e] = (__bf16)x4[e]; f[e + 4] = (__bf16)xo[e]; }
    } else if (q == 1) {
      const float* rp = z_eff + bcol * 12;
      f32x4 r0 = *(const f32x4*)(rp);
      f32x4 r1 = *(const f32x4*)(rp + 4);
#pragma unroll
      for (int e = 0; e < 4; ++e) { f[e] = (__bf16)r0[e]; f[e + 4] = (__bf16)r1[e]; }
    }
#pragma unroll
    for (int tt = 0; tt < 2; ++tt) {
      f32x4 c = __builtin_amdgcn_mfma_f32_16x16x32_bf16(w1ff[tt], f, c1init[tt], 0, 0, 0);
      union { __bf16 h4[4]; unsigned long long u; } pk;
#pragma unroll
      for (int e = 0; e < 4; ++e) {
        float v = c[e];
        v = (v > 0.f) ? v : (__expf(v) - 1.0f);
        pk.h4[e] = (__bf16)v;
      }
      if (live)
        *(unsigned long long*)(h_a + bcol * 264 + wid * 32 + tt * 16 + q * 4) = pk.u;
    }
    wg_barrier();

    // ---- phase B: wave-2 publishes z_eff(i+1) (WAR: 1 bar after phase-A reads;
    //      RAW: 2 bars before next phase-A read), then layer 2 ----
    if (zprod) {
      tn_hold = t_g[i + 1];
      bool jmp = (tn_hold >= ev1);
      float2 zev = make_float2(jmp ? zjf.x : zpre.x, jmp ? zjf.y : zpre.y);
      *(float2*)(z_eff + m1 * 12 + d0) = zev;
    } else {
      tn_hold = t_g[i + 1];
    }
    layer(h_a, h_b, w2f, b2v);
    wg_barrier();

    // ---- phase C: layer 3 (-> h_a) + fused W4 partial on OWN 32 cols -> p4 ----
    layer(h_b, h_a, w3f, b3v);
    {
      bf16x8 h4r = ((const bf16x8*)h_a)[rrow * 33 + wid * 4 + q];  // same-wave RAW
      f32x4 c = {0.f, 0.f, 0.f, 0.f};
      c = __builtin_amdgcn_mfma_f32_16x16x32_bf16(w4f, h4r, c, 0, 0, 0);
      if (q < 2 && live)
        *(f32x4*)(p4 + wid * 128 + bcol * 8 + q * 4) = c;
    }
    wg_barrier();
  }
}

extern "C" void kernel_launch(void* const* d_in, const int* in_sizes, int n_in,
                              void* d_out, int out_size, void* d_ws, size_t ws_size,
                              hipStream_t stream) {
  const float* t  = (const float*)d_in[0];
  const float* x  = (const float*)d_in[1];
  const float* z  = (const float*)d_in[2];
  const float* ev = (const float*)d_in[3];
  const float* zj = (const float*)d_in[4];
  const float* W1 = (const float*)d_in[5];
  const float* b1 = (const float*)d_in[6];
  const float* W2 = (const float*)d_in[7];
  const float* b2 = (const float*)d_in[8];
  const float* W3 = (const float*)d_in[9];
  const float* b3 = (const float*)d_in[10];
  const float* W4 = (const float*)d_in[11];
  const float* b4 = (const float*)d_in[12];
  __bf16* ws = (__bf16*)d_ws;
  float* out = (float*)d_out;

  prep_weights<<<592, 256, 0, stream>>>(W1, b1, W2, W3, W4, ws);
  ode_main<<<256, 512, 0, stream>>>(t, x, z, ev, zj, b2, b3, b4, ws, out);
}

// Round 16
// 1587.265 us; speedup vs baseline: 1.1807x; 1.1807x over previous
//
#include <hip/hip_runtime.h>
#include <cstdint>
#include <cstddef>

typedef __bf16 bf16x8 __attribute__((ext_vector_type(8)));
typedef float f32x4 __attribute__((ext_vector_type(4)));

#define HD 256
#define TLEN 1000
#define NSTEP 999
#define BTILE 4

// ws layout (bf16 elements): W1F | W1C | W2R | W3R | W4R, fragment-ordered.
// W1F+W1C exactly fill r4's old W1R region; W2R/W3R/W4R offsets unchanged.
#define W1F_OFF 0
#define W1C_OFF 8192
#define W2R_OFF 16384
#define W3R_OFF 81920
#define W4R_OFF 147456
#define WS_ELEMS 151552

__device__ __forceinline__ void wg_barrier() {
  // LDS-only drain + barrier: do NOT force vmcnt(0) like __syncthreads does,
  // so the z-prefetch / out-stores stay in flight across layer barriers.
  asm volatile("s_waitcnt lgkmcnt(0)\n\ts_barrier" ::: "memory");
}

// Repack fp32 weights -> bf16 MFMA A-fragments in ws.
// Layer-1 algebraic fold (verified r13, absmax 0.25):
//   h1_pre = x*W1x + z_eff*W1z + c1
//   W1F: k0-7  = W1x = W1[16+k]+W1[32+k]
//        k8-15 = W1z = W1[24+(k-8)]+W1[40+(k-8)], k16-31 = 0
//   W1C (consumed ONCE pre-loop into c1init):
//        k0-7  = W1[k]-W1[16+k], k8-15 = W1[8+(k-8)]-W1[24+(k-8)],
//        k16   = b1 (fed by constant-1), rest 0
// W2/W3/W4 fragment layout unchanged from r4:
//   k = kb*32 + (lane>>4)*8 + j ; n = w*32 + tt*16 + (lane&15)
__global__ void prep_weights(const float* __restrict__ W1, const float* __restrict__ b1,
                             const float* __restrict__ W2, const float* __restrict__ W3,
                             const float* __restrict__ W4, __bf16* __restrict__ ws) {
  int tid = blockIdx.x * blockDim.x + threadIdx.x;
  if (tid >= WS_ELEMS) return;
  float val = 0.0f;
  if (tid < W1C_OFF) {                       // W1F: 8w x 2tt x 64lane x 8j
    int t = tid;
    int j = t & 7, lane = (t >> 3) & 63, tt = (t >> 9) & 1, w = (t >> 10) & 7;
    int k = ((lane >> 4) * 8) + j;
    int n = w * 32 + tt * 16 + (lane & 15);
    if (k < 8) val = W1[(16 + k) * HD + n] + W1[(32 + k) * HD + n];
    else if (k < 16) { int d = k - 8; val = W1[(24 + d) * HD + n] + W1[(40 + d) * HD + n]; }
  } else if (tid < W2R_OFF) {                // W1C
    int t = tid - W1C_OFF;
    int j = t & 7, lane = (t >> 3) & 63, tt = (t >> 9) & 1, w = (t >> 10) & 7;
    int k = ((lane >> 4) * 8) + j;
    int n = w * 32 + tt * 16 + (lane & 15);
    if (k < 8) val = W1[k * HD + n] - W1[(16 + k) * HD + n];
    else if (k < 16) { int d = k - 8; val = W1[(8 + d) * HD + n] - W1[(24 + d) * HD + n]; }
    else if (k == 16) val = b1[n];
  } else if (tid < W3R_OFF) {                // W2R: 8w x 8kb x 2tt x 64 x 8
    int t = tid - W2R_OFF;
    int j = t & 7, lane = (t >> 3) & 63, tt = (t >> 9) & 1, kb = (t >> 10) & 7, w = (t >> 13) & 7;
    int k = kb * 32 + ((lane >> 4) * 8) + j;
    int n = w * 32 + tt * 16 + (lane & 15);
    val = W2[k * HD + n];
  } else if (tid < W4R_OFF) {                // W3R
    int t = tid - W3R_OFF;
    int j = t & 7, lane = (t >> 3) & 63, tt = (t >> 9) & 1, kb = (t >> 10) & 7, w = (t >> 13) & 7;
    int k = kb * 32 + ((lane >> 4) * 8) + j;
    int n = w * 32 + tt * 16 + (lane & 15);
    val = W3[k * HD + n];
  } else {                                   // W4R: 8kb x 64 x 8, N padded 8->16 with zeros
    int t = tid - W4R_OFF;
    int j = t & 7, lane = (t >> 3) & 63, kb = (t >> 9) & 7;
    int k = kb * 32 + ((lane >> 4) * 8) + j;
    int n = lane & 15;
    val = (n < 8) ? W4[k * 8 + n] : 0.0f;
  }
  ws[tid] = (__bf16)val;
}

// r15 post-mortem: D-merge falsified in 4 forms (r5/r8/r10/r15); the broadcast
// reads cost 7e7 bank-conflict cycles and the all-wave reduce fattened every
// wave's critical path. This is the EXACT r13 champion revert (1585us):
// r4 schedule (4 barriers, wave-0 reduce, wave-2 z producer, exec-masked
// LDS reads) + layer-1 fold (phase 1 = 2 MFMAs, c1 folded once pre-loop
// into the MFMA C-initializer via W1C). VGPR 116, conflicts 7.9e5.
__global__ __launch_bounds__(512, 2) void ode_main(
    const float* __restrict__ t_g, const float* __restrict__ x_g,
    const float* __restrict__ z_g, const float* __restrict__ ev_g,
    const float* __restrict__ zj_g, const float* __restrict__ b2_g,
    const float* __restrict__ b3_g, const float* __restrict__ b4_g,
    const __bf16* __restrict__ ws, float* __restrict__ out) {
  __shared__ __align__(16) __bf16 h_a[16 * 264];   // 16 rows kept (4 live), row 528B
  __shared__ __align__(16) __bf16 h_b[16 * 264];
  __shared__ __align__(16) float p4[8 * 16 * 8];   // [wave][bcol][dim]
  __shared__ __align__(16) float x_cur[16 * 12];
  __shared__ __align__(16) float z_eff[16 * 12];
  __shared__ __align__(16) float x0s[16 * 12];
  __shared__ __align__(16) float z0s[16 * 12];
  __shared__ __align__(16) float zjs[16 * 12];
  __shared__ float evs[16];

  const int tid  = threadIdx.x;
  const int lane = tid & 63;
  const int wid  = tid >> 6;     // 8 waves; wave w owns hidden cols [32w, 32w+32)
  const int bcol = lane & 15;    // B/C-operand column; batch row if < BTILE, dead otherwise
  const int q    = lane >> 4;    // quad
  const int b0   = blockIdx.x * BTILE;
  const bool live = bcol < BTILE;

  // ---- stage per-batch constants (rows >= BTILE zeroed: dead cols stay exact 0) ----
  if (tid < 128) {
    int m = tid >> 3, d = tid & 7;
    if (m < BTILE) {
      size_t gb = (size_t)(b0 + m);
      float x0 = x_g[gb * (TLEN * 8) + d];
      float z0 = z_g[gb * (TLEN * 8) + d];
      x0s[m * 12 + d] = x0;
      z0s[m * 12 + d] = z0;
      x_cur[m * 12 + d] = x0;
      zjs[m * 12 + d] = zj_g[gb * 8 + d];
      out[gb * (TLEN * 8) + d] = x0;         // sol[:,0] = x0
      if (d == 0) evs[m] = ev_g[gb];
    } else {
      x0s[m * 12 + d] = 0.f;
      z0s[m * 12 + d] = 0.f;
      x_cur[m * 12 + d] = 0.f;
      zjs[m * 12 + d] = 0.f;
      if (d == 0) evs[m] = 0.f;
    }
  }
  __syncthreads();

  if (tid < 128) {  // z_eff for step 0 (rows >= BTILE resolve to 0)
    int m = tid >> 3, d = tid & 7;
    float t0 = t_g[0];
    z_eff[m * 12 + d] = (t0 >= evs[m]) ? zjs[m * 12 + d] : z0s[m * 12 + d];
  }

  // ---- resident weight fragments (A-operand layout) ----
  const bf16x8* wsv = (const bf16x8*)ws;
  bf16x8 w1ff[2], w2f[8][2], w3f[8][2];
#pragma unroll
  for (int tt = 0; tt < 2; ++tt)
    w1ff[tt] = wsv[(W1F_OFF / 8) + (wid * 2 + tt) * 64 + lane];
#pragma unroll
  for (int kb = 0; kb < 8; ++kb)
#pragma unroll
    for (int tt = 0; tt < 2; ++tt) {
      w2f[kb][tt] = wsv[(W2R_OFF / 8) + ((wid * 8 + kb) * 2 + tt) * 64 + lane];
      w3f[kb][tt] = wsv[(W3R_OFF / 8) + ((wid * 8 + kb) * 2 + tt) * 64 + lane];
    }
  // W4 k-slice for this wave: k in [32*wid, 32*wid+32)
  bf16x8 w4f = wsv[(W4R_OFF / 8) + wid * 64 + lane];

  // biases as C-init: lane's 4 C rows are hidden n = wid*32 + tt*16 + q*4 + e
  f32x4 b2v[2], b3v[2];
#pragma unroll
  for (int tt = 0; tt < 2; ++tt) {
    int n0 = wid * 32 + tt * 16 + q * 4;
    b2v[tt] = *(const f32x4*)(b2_g + n0);
    b3v[tt] = *(const f32x4*)(b3_g + n0);
  }
  float b4l = (tid < 64) ? b4_g[tid & 7] : 0.0f;

  // wave-2 personals (z_eff producer): lanes 0..BTILE*4-1 cover (m 0..BTILE-1) x (d pairs)
  const int m1 = lane >> 2;          // batch row
  const int d0 = (lane & 3) * 2;
  float2 zjf = make_float2(0.f, 0.f);
  float ev1 = 0.f;
  const bool zprod = (wid == 2) && (lane < BTILE * 4);
  if (zprod) {
    zjf.x = zjs[m1 * 12 + d0];
    zjf.y = zjs[m1 * 12 + d0 + 1];
    ev1 = evs[m1];
  }

  bf16x8 zf;
#pragma unroll
  for (int e = 0; e < 8; ++e) zf[e] = (__bf16)0.f;

  // ---- c1init: step-invariant layer-1 term via ONE-SHOT MFMA on W1C ----
  // cfrag: q0 = x0 (8 dims), q1 = z0, q2 elem0 = 1 (b1 row at k=16), q3 = 0
  f32x4 c1init[2];
  {
    bf16x8 cfrag = zf;
    if (q == 0) {
      const float* xp = x0s + bcol * 12;
#pragma unroll
      for (int e = 0; e < 4; ++e) { cfrag[e] = (__bf16)xp[e]; cfrag[e + 4] = (__bf16)xp[e + 4]; }
    } else if (q == 1) {
      const float* zp = z0s + bcol * 12;
#pragma unroll
      for (int e = 0; e < 4; ++e) { cfrag[e] = (__bf16)zp[e]; cfrag[e + 4] = (__bf16)zp[e + 4]; }
    } else if (q == 2) {
      cfrag[0] = (__bf16)1.0f;
    }
    f32x4 z4 = {0.f, 0.f, 0.f, 0.f};
#pragma unroll
    for (int tt = 0; tt < 2; ++tt) {
      bf16x8 w1cf = wsv[(W1C_OFF / 8) + (wid * 2 + tt) * 64 + lane];
      c1init[tt] = __builtin_amdgcn_mfma_f32_16x16x32_bf16(w1cf, cfrag, z4, 0, 0, 0);
    }
  }

  __syncthreads();

  float tc = t_g[0];

  // persistent masked-read destinations: dead lanes keep zeros forever.
  bf16x8 bfr[8];
#pragma unroll
  for (int kb = 0; kb < 8; ++kb) bfr[kb] = zf;
  bf16x8 h4r = zf;

  auto layer = [&](const __bf16* src, __bf16* dst, const bf16x8 (*wf)[2], const f32x4* bv) {
    const bf16x8* hp = (const bf16x8*)src;
    if (live) {   // masked reads: dead lanes generate no LDS traffic
#pragma unroll
      for (int kb = 0; kb < 8; ++kb) bfr[kb] = hp[bcol * 33 + kb * 4 + q];  // ds_read_b128 x8
    }
#pragma unroll
    for (int tt = 0; tt < 2; ++tt) {
      f32x4 c = bv[tt];
#pragma unroll
      for (int kb = 0; kb < 8; ++kb)
        c = __builtin_amdgcn_mfma_f32_16x16x32_bf16(wf[kb][tt], bfr[kb], c, 0, 0, 0);
      union { __bf16 h4[4]; unsigned long long u; } pk;
#pragma unroll
      for (int e = 0; e < 4; ++e) {
        float v = c[e];
        v = (v > 0.f) ? v : (__expf(v) - 1.0f);  // ELU
        pk.h4[e] = (__bf16)v;
      }
      // 4 consecutive hidden cols for batch bcol -> one ds_write_b64
      if (live)
        *(unsigned long long*)(dst + bcol * 264 + wid * 32 + tt * 16 + q * 4) = pk.u;
    }
  };

#pragma unroll 1
  for (int i = 0; i < NSTEP; ++i) {
    float tn = t_g[i + 1];
    float2 zpre = make_float2(0.f, 0.f);
    if (zprod)  // prefetch z[:, i+1]; consumed in phase 4 of this step
      zpre = *(const float2*)(z_g + ((size_t)(b0 + m1) * TLEN + (i + 1)) * 8 + d0);

    // ---- phase 1: folded layer 1 — 2 MFMAs, C-init = c1init ----
    // B-frag: q0 = x_cur (k0-7), q1 = z_eff (k8-15), q2/q3 = 0
    {
      bf16x8 f = zf;
      if (q < 2) {
        const float* rp = ((q & 1) ? z_eff : x_cur) + bcol * 12;
        f32x4 r0 = *(const f32x4*)(rp);
        f32x4 r1 = *(const f32x4*)(rp + 4);
#pragma unroll
        for (int e = 0; e < 4; ++e) { f[e] = (__bf16)r0[e]; f[e + 4] = (__bf16)r1[e]; }
      }
#pragma unroll
      for (int tt = 0; tt < 2; ++tt) {
        f32x4 c = __builtin_amdgcn_mfma_f32_16x16x32_bf16(w1ff[tt], f, c1init[tt], 0, 0, 0);
        union { __bf16 h4[4]; unsigned long long u; } pk;
#pragma unroll
        for (int e = 0; e < 4; ++e) {
          float v = c[e];
          v = (v > 0.f) ? v : (__expf(v) - 1.0f);
          pk.h4[e] = (__bf16)v;
        }
        if (live)
          *(unsigned long long*)(h_a + bcol * 264 + wid * 32 + tt * 16 + q * 4) = pk.u;
      }
    }
    wg_barrier();
    layer(h_a, h_b, w2f, b2v);   // phase 2: layer 2
    wg_barrier();
    layer(h_b, h_a, w3f, b3v);   // phase 3: layer 3 (h3 -> h_a)

    // ---- phase 3b (fused, no barrier): layer-4 partial on OWN 32 columns ----
    {
      const bf16x8* hp = (const bf16x8*)h_a;
      if (live) h4r = hp[bcol * 33 + wid * 4 + q];
      f32x4 c = {0.f, 0.f, 0.f, 0.f};
      c = __builtin_amdgcn_mfma_f32_16x16x32_bf16(w4f, h4r, c, 0, 0, 0);
      if (q < 2 && live)  // valid out rows n = q*4+e < 8
        *(f32x4*)(p4 + wid * 128 + bcol * 8 + q * 4) = c;
    }
    wg_barrier();

    // ---- phase 4: reduce + Euler (wave 0, rows < BTILE), z_eff(i+1) (wave 2) ----
    float dt = tn - tc;
    if (tid < 64) {
      int m = tid >> 3, d = tid & 7;
      if (m < BTILE) {                 // live batch rows only; rows >= BTILE stay 0
        float s = b4l;
#pragma unroll
        for (int j = 0; j < 8; ++j) s += p4[j * 128 + m * 8 + d];
        float xn = x_cur[m * 12 + d] + dt * s;
        x_cur[m * 12 + d] = xn;
        out[(size_t)(b0 + m) * (TLEN * 8) + (size_t)(i + 1) * 8 + d] = xn;
      }
    } else if (zprod) {
      bool jmp = (tn >= ev1);
      float2 zev = make_float2(jmp ? zjf.x : zpre.x, jmp ? zjf.y : zpre.y);
      *(float2*)(z_eff + m1 * 12 + d0) = zev;
    }
    tc = tn;
    wg_barrier();
  }
}

extern "C" void kernel_launch(void* const* d_in, const int* in_sizes, int n_in,
                              void* d_out, int out_size, void* d_ws, size_t ws_size,
                              hipStream_t stream) {
  const float* t  = (const float*)d_in[0];
  const float* x  = (const float*)d_in[1];
  const float* z  = (const float*)d_in[2];
  const float* ev = (const float*)d_in[3];
  const float* zj = (const float*)d_in[4];
  const float* W1 = (const float*)d_in[5];
  const float* b1 = (const float*)d_in[6];
  const float* W2 = (const float*)d_in[7];
  const float* b2 = (const float*)d_in[8];
  const float* W3 = (const float*)d_in[9];
  const float* b3 = (const float*)d_in[10];
  const float* W4 = (const float*)d_in[11];
  const float* b4 = (const float*)d_in[12];
  __bf16* ws = (__bf16*)d_ws;
  float* out = (float*)d_out;

  prep_weights<<<592, 256, 0, stream>>>(W1, b1, W2, W3, W4, ws);
  ode_main<<<256, 512, 0, stream>>>(t, x, z, ev, zj, b2, b3, b4, ws, out);
}